// Round 1
// baseline (130.817 us; speedup 1.0000x reference)
//
#include <hip/hip_runtime.h>
#include <math.h>

#define S_LEN 56
#define DH 128
#define SP 64

typedef float f32x4 __attribute__((ext_vector_type(4)));
typedef unsigned short u16x8 __attribute__((ext_vector_type(8)));
typedef unsigned short u16x4 __attribute__((ext_vector_type(4)));

__device__ __forceinline__ unsigned short f2bf(float f) {
  unsigned int u = __builtin_bit_cast(unsigned int, f);
  u += 0x7fffu + ((u >> 16) & 1u);  // RNE
  return (unsigned short)(u >> 16);
}

// MFMA wrapper: the gfx950 builtin signature may want short-vectors or
// __bf16-vectors depending on toolchain; SFINAE-select whichever compiles.
template <typename V>
__device__ __forceinline__ auto mfma_sel(V a, V b, f32x4 c, int)
    -> decltype(__builtin_amdgcn_mfma_f32_16x16x32_bf16(a, b, c, 0, 0, 0)) {
  return __builtin_amdgcn_mfma_f32_16x16x32_bf16(a, b, c, 0, 0, 0);
}
template <typename V, typename E = __bf16>
__device__ __forceinline__ f32x4 mfma_sel(V a, V b, f32x4 c, long) {
  typedef E bfv __attribute__((ext_vector_type(8)));
  return __builtin_amdgcn_mfma_f32_16x16x32_bf16(
      __builtin_bit_cast(bfv, a), __builtin_bit_cast(bfv, b), c, 0, 0, 0);
}
__device__ __forceinline__ f32x4 MFMA(u16x8 a, u16x8 b, f32x4 c) {
  return mfma_sel(a, b, c, 0);
}

// XOR swizzle for row-major LDS tiles (row stride 2^LRB bytes); kills the
// stride-256B/128B bank conflict on ds_read_b128 (Guideline 4).
template <int LRB>
__device__ __forceinline__ int swz(int row, int col) {
  int byteoff = (row << LRB) + (col << 1);
  byteoff ^= (row & 7) << 4;
  return byteoff >> 1;  // ushort index
}

__global__ void conv_w(const float* __restrict__ wq, const float* __restrict__ wk,
                       const float* __restrict__ wv, const float* __restrict__ wo,
                       unsigned short* __restrict__ o) {
  int i = blockIdx.x * 256 + threadIdx.x;  // 0..65535
  int m = i >> 14, r = i & 16383;
  const float* src = (m == 0) ? wq : (m == 1) ? wk : (m == 2) ? wv : wo;
  o[i] = f2bf(src[r]);
}

__global__ __launch_bounds__(256, 2) void tb_fused(
    const float* __restrict__ xg, const unsigned short* __restrict__ wbf,
    const int* __restrict__ lens, float* __restrict__ outg,
    float* __restrict__ attng) {
  __shared__ __align__(16) unsigned short xs[SP * DH];  // x, later reused for O
  __shared__ __align__(16) unsigned short qs[SP * DH];
  __shared__ __align__(16) unsigned short ks[SP * DH];
  __shared__ __align__(16) unsigned short vt[DH * SP];  // V transposed [d][k']
  __shared__ __align__(16) unsigned short ps[SP * SP];  // P*sqrt(len) bf16

  const int b = blockIdx.x;
  const int tid = threadIdx.x;
  const int lane = tid & 63;
  const int w = tid >> 6;     // wave 0..3
  const int l15 = lane & 15;
  const int lq = lane >> 4;   // 0..3
  const int n0w = w << 5;     // 32-col slice per wave for n-partitioned GEMMs

  const float* __restrict__ xb = xg + (size_t)b * (S_LEN * DH);

  // ---- x -> LDS bf16, rows 56..63 zeroed ----
#pragma unroll
  for (int i = 0; i < 8; ++i) {
    int e4 = tid + (i << 8);          // float4 index, 0..2047
    int row = e4 >> 5;
    int col = (e4 & 31) << 2;
    u16x4 h = {0, 0, 0, 0};
    if (row < S_LEN) {
      f32x4 v = *(const f32x4*)(xb + (e4 << 2));
      h[0] = f2bf(v[0]); h[1] = f2bf(v[1]); h[2] = f2bf(v[2]); h[3] = f2bf(v[3]);
    }
    *(u16x4*)&xs[swz<8>(row, col)] = h;
  }
  __syncthreads();

  // ---- preload x A-fragments (all 4 m-tiles x 4 k-tiles) ----
  u16x8 af[4][4];
#pragma unroll
  for (int mt = 0; mt < 4; ++mt)
#pragma unroll
    for (int kt = 0; kt < 4; ++kt)
      af[mt][kt] = *(const u16x8*)&xs[swz<8>((mt << 4) + l15, (kt << 5) + (lq << 3))];

  // ---- GEMM1: Q,K,V = x @ W^T (wave w owns cols [32w,32w+32)) ----
#pragma unroll
  for (int mat = 0; mat < 3; ++mat) {
    const unsigned short* __restrict__ wm = wbf + mat * (DH * DH);
    f32x4 acc[4][2];
#pragma unroll
    for (int mt = 0; mt < 4; ++mt)
#pragma unroll
      for (int nt = 0; nt < 2; ++nt) acc[mt][nt] = f32x4{0.f, 0.f, 0.f, 0.f};
#pragma unroll
    for (int kt = 0; kt < 4; ++kt) {
      u16x8 bfrag[2];
#pragma unroll
      for (int nt = 0; nt < 2; ++nt)
        bfrag[nt] = *(const u16x8*)&wm[(n0w + (nt << 4) + l15) * DH + (kt << 5) + (lq << 3)];
#pragma unroll
      for (int mt = 0; mt < 4; ++mt)
#pragma unroll
        for (int nt = 0; nt < 2; ++nt)
          acc[mt][nt] = MFMA(af[mt][kt], bfrag[nt], acc[mt][nt]);
    }
#pragma unroll
    for (int mt = 0; mt < 4; ++mt)
#pragma unroll
      for (int nt = 0; nt < 2; ++nt) {
        int colg = n0w + (nt << 4) + l15;       // output col (d)
        int rowb = (mt << 4) + (lq << 2);       // output row base (s / k')
        if (mat == 0) {
#pragma unroll
          for (int r = 0; r < 4; ++r) qs[swz<8>(rowb + r, colg)] = f2bf(acc[mt][nt][r]);
        } else if (mat == 1) {
#pragma unroll
          for (int r = 0; r < 4; ++r) ks[swz<8>(rowb + r, colg)] = f2bf(acc[mt][nt][r]);
        } else {  // V stored transposed: vt[d][k']
          u16x4 h;
#pragma unroll
          for (int r = 0; r < 4; ++r) h[r] = f2bf(acc[mt][nt][r]);
          *(u16x4*)&vt[swz<7>(colg, rowb)] = h;
        }
      }
  }
  __syncthreads();

  // ---- GEMM2: E = Q K^T / sqrt(D)  (wave w owns q-rows [16w,16w+16)) ----
  u16x8 aq[4];
#pragma unroll
  for (int kt = 0; kt < 4; ++kt)
    aq[kt] = *(const u16x8*)&qs[swz<8>((w << 4) + l15, (kt << 5) + (lq << 3))];
  f32x4 e[4];
#pragma unroll
  for (int nt = 0; nt < 4; ++nt) {
    f32x4 a = f32x4{0.f, 0.f, 0.f, 0.f};
#pragma unroll
    for (int kt = 0; kt < 4; ++kt) {
      u16x8 bk = *(const u16x8*)&ks[swz<8>((nt << 4) + l15, (kt << 5) + (lq << 3))];
      a = MFMA(aq[kt], bk, a);
    }
    e[nt] = a;
  }

  const int len = lens[b];
  const float sca = 0.08838834764831845f;  // 1/sqrt(128)
#pragma unroll
  for (int nt = 0; nt < 4; ++nt) {
    int kcol = (nt << 4) + l15;
    bool valid = kcol < len;
#pragma unroll
    for (int r = 0; r < 4; ++r) e[nt][r] = valid ? e[nt][r] * sca : -1e30f;
  }

  // wave-parallel softmax: each row lives in one 16-lane group (reg r)
  float inv[4];
#pragma unroll
  for (int r = 0; r < 4; ++r) {
    float m = fmaxf(fmaxf(e[0][r], e[1][r]), fmaxf(e[2][r], e[3][r]));
#pragma unroll
    for (int off = 1; off < 16; off <<= 1) m = fmaxf(m, __shfl_xor(m, off, 64));
    float s = 0.f;
#pragma unroll
    for (int nt = 0; nt < 4; ++nt) {
      float p = __expf(e[nt][r] - m);
      e[nt][r] = p;
      s += p;
    }
#pragma unroll
    for (int off = 1; off < 16; off <<= 1) s += __shfl_xor(s, off, 64);
    inv[r] = 1.f / s;
  }

  const float slen = sqrtf((float)len);
  float* __restrict__ ab = attng + (size_t)b * (S_LEN * S_LEN);
#pragma unroll
  for (int nt = 0; nt < 4; ++nt) {
    int kcol = (nt << 4) + l15;
#pragma unroll
    for (int r = 0; r < 4; ++r) {
      int q = (w << 4) + (lq << 2) + r;
      float p = e[nt][r] * inv[r];
      if (q < S_LEN && kcol < S_LEN) ab[q * S_LEN + kcol] = p;  // attention output
      ps[swz<7>(q, kcol)] = f2bf(p * slen);                     // P' for PV
    }
  }
  __syncthreads();

  // ---- GEMM3: O = P' V  (wave w owns q-rows [16w,16w+16)); overwrite xs ----
  u16x8 ap[2];
#pragma unroll
  for (int kt = 0; kt < 2; ++kt)
    ap[kt] = *(const u16x8*)&ps[swz<7>((w << 4) + l15, (kt << 5) + (lq << 3))];
#pragma unroll
  for (int nt = 0; nt < 8; ++nt) {
    f32x4 a = f32x4{0.f, 0.f, 0.f, 0.f};
#pragma unroll
    for (int kt = 0; kt < 2; ++kt) {
      u16x8 bv = *(const u16x8*)&vt[swz<7>((nt << 4) + l15, (kt << 5) + (lq << 3))];
      a = MFMA(ap[kt], bv, a);
    }
    int dcol = (nt << 4) + l15;
    int rowb = (w << 4) + (lq << 2);
#pragma unroll
    for (int r = 0; r < 4; ++r) xs[swz<8>(rowb + r, dcol)] = f2bf(a[r]);
  }
  __syncthreads();

  // ---- GEMM4: out = O @ Wo^T (wave w owns cols [32w,32w+32)) ----
  const unsigned short* __restrict__ wo = wbf + 3 * (DH * DH);
  u16x8 ao[4][4];
#pragma unroll
  for (int mt = 0; mt < 4; ++mt)
#pragma unroll
    for (int kt = 0; kt < 4; ++kt)
      ao[mt][kt] = *(const u16x8*)&xs[swz<8>((mt << 4) + l15, (kt << 5) + (lq << 3))];
  float* __restrict__ ob = outg + (size_t)b * (S_LEN * DH);
#pragma unroll
  for (int nt = 0; nt < 2; ++nt) {
    int dcol = n0w + (nt << 4) + l15;
    f32x4 acc[4];
#pragma unroll
    for (int mt = 0; mt < 4; ++mt) acc[mt] = f32x4{0.f, 0.f, 0.f, 0.f};
#pragma unroll
    for (int kt = 0; kt < 4; ++kt) {
      u16x8 bo = *(const u16x8*)&wo[dcol * DH + (kt << 5) + (lq << 3)];
#pragma unroll
      for (int mt = 0; mt < 4; ++mt) acc[mt] = MFMA(ao[mt][kt], bo, acc[mt]);
    }
#pragma unroll
    for (int mt = 0; mt < 4; ++mt) {
      int rowb = (mt << 4) + (lq << 2);
#pragma unroll
      for (int r = 0; r < 4; ++r) {
        int s = rowb + r;
        if (s < S_LEN) ob[s * DH + dcol] = acc[mt][r];
      }
    }
  }
}

extern "C" void kernel_launch(void* const* d_in, const int* in_sizes, int n_in,
                              void* d_out, int out_size, void* d_ws, size_t ws_size,
                              hipStream_t stream) {
  const float* x  = (const float*)d_in[0];
  const float* wq = (const float*)d_in[1];
  const float* wk = (const float*)d_in[2];
  const float* wv = (const float*)d_in[3];
  const float* wo = (const float*)d_in[4];
  // d_in[5] = mask (redundant with len_sequence; unused)
  const int* lens = (const int*)d_in[6];
  const int B = in_sizes[6];  // 4096

  float* out = (float*)d_out;
  float* attn = out + (size_t)B * S_LEN * DH;
  unsigned short* wbf = (unsigned short*)d_ws;  // 4 x 128 x 128 bf16 = 128 KB

  conv_w<<<256, 256, 0, stream>>>(wq, wk, wv, wo, wbf);
  tb_fused<<<B, 256, 0, stream>>>(x, wbf, lens, out, attn);
}